// Round 4
// baseline (3026.341 us; speedup 1.0000x reference)
//
#include <hip/hip_runtime.h>
#include <math.h>

// Problem constants
#define Bb 64
#define Tt 512
#define Ee 128
#define Hq 256
#define G3 768      // 3*H
#define KK 16

// GRU recurrence tuning
#define RREG 112                 // k-slabs held in VGPRs per thread
#define NSTREAM (256 - RREG)     // k-slabs streamed from L2 each step

// Workspace layout (in floats).  Budget: 256 MiB = 67,108,864 floats.
// h-states are written IN PLACE into the consumed xp rows (first 256 of 768),
// so no separate hcat buffer is needed.
#define OFF_WTF  0
#define OFF_WTB  196608                        // 768*256
#define OFF_XPF  393216
#define OFF_XPB  (OFF_XPF + 25165824)          // 32768*768
#define OFF_EM   (OFF_XPB + 25165824)
#define WS_FLOATS ((size_t)(OFF_EM + 524288))  // = 51,249,152 floats = 205 MB

// ---------------------------------------------------------------------------
// Transpose w_hh (768x256) -> wt (256x768) so per-k slabs are coalesced.
__global__ __launch_bounds__(256) void transpose_whh(const float* __restrict__ w,
                                                     float* __restrict__ wt)
{
    const int idx = blockIdx.x * 256 + threadIdx.x;
    if (idx < G3 * Hq) {
        const int jrow = idx >> 8;     // gate row 0..767
        const int k    = idx & 255;    // k 0..255
        wt[(size_t)k * G3 + jrow] = w[idx];
    }
}

// ---------------------------------------------------------------------------
// Fused embedding-gather + input projection for both directions.
// xp[m][g] = sum_k embed[x[m]][k] * w_ih[g][k] + b_ih[g] + (g<512 ? b_hh[g] : 0)
// M=32768 rows, N=1536 (768 fwd | 768 bwd), K=128.  64x64 tile, 256 thr, 4x4/thr.
__global__ __launch_bounds__(256) void proj_kernel(
    const int* __restrict__ x, const float* __restrict__ embed,
    const float* __restrict__ wf, const float* __restrict__ wb,
    const float* __restrict__ bihf, const float* __restrict__ bhhf,
    const float* __restrict__ bihb, const float* __restrict__ bhhb,
    float* __restrict__ xpf, float* __restrict__ xpb)
{
    __shared__ float As[64][66];   // [k_local][mi]
    __shared__ float Bs[64][66];   // [k_local][ni]
    const int bi = blockIdx.x;
    const int mb = bi / 24, nb = bi % 24;
    const int m0 = mb * 64, n0 = nb * 64;
    const int tid = threadIdx.x;
    const int tx = tid & 15, ty = tid >> 4;
    float acc[4][4] = {};

    for (int kc = 0; kc < 128; kc += 64) {
        __syncthreads();
        // stage A (embedding rows, transposed into LDS)
        for (int it = 0; it < 4; ++it) {
            const int l  = it * 256 + tid;        // 0..1023
            const int mi = l >> 4;
            const int k4 = (l & 15) << 2;
            const int row = x[m0 + mi];
            const float4 v = *(const float4*)(embed + (size_t)row * Ee + kc + k4);
            As[k4 + 0][mi] = v.x; As[k4 + 1][mi] = v.y;
            As[k4 + 2][mi] = v.z; As[k4 + 3][mi] = v.w;
        }
        // stage B (w_ih rows for this gate tile, transposed)
        for (int it = 0; it < 4; ++it) {
            const int l  = it * 256 + tid;
            const int ni = l >> 4;
            const int k4 = (l & 15) << 2;
            const int g  = n0 + ni;
            const float* wsrc = (g < G3) ? (wf + (size_t)g * Ee)
                                         : (wb + (size_t)(g - G3) * Ee);
            const float4 v = *(const float4*)(wsrc + kc + k4);
            Bs[k4 + 0][ni] = v.x; Bs[k4 + 1][ni] = v.y;
            Bs[k4 + 2][ni] = v.z; Bs[k4 + 3][ni] = v.w;
        }
        __syncthreads();
        for (int k = 0; k < 64; ++k) {
            const float a0 = As[k][ty];      const float a1 = As[k][ty + 16];
            const float a2 = As[k][ty + 32]; const float a3 = As[k][ty + 48];
            const float b0 = Bs[k][tx];      const float b1 = Bs[k][tx + 16];
            const float b2 = Bs[k][tx + 32]; const float b3 = Bs[k][tx + 48];
            acc[0][0] += a0 * b0; acc[0][1] += a0 * b1; acc[0][2] += a0 * b2; acc[0][3] += a0 * b3;
            acc[1][0] += a1 * b0; acc[1][1] += a1 * b1; acc[1][2] += a1 * b2; acc[1][3] += a1 * b3;
            acc[2][0] += a2 * b0; acc[2][1] += a2 * b1; acc[2][2] += a2 * b2; acc[2][3] += a2 * b3;
            acc[3][0] += a3 * b0; acc[3][1] += a3 * b1; acc[3][2] += a3 * b2; acc[3][3] += a3 * b3;
        }
    }
#pragma unroll
    for (int i = 0; i < 4; ++i) {
        const int m = m0 + ty + 16 * i;
#pragma unroll
        for (int c = 0; c < 4; ++c) {
            const int g = n0 + tx + 16 * c;
            const float v = acc[i][c];
            if (g < G3) {
                const float bias = bihf[g] + (g < 2 * Hq ? bhhf[g] : 0.0f);
                xpf[(size_t)m * G3 + g] = v + bias;
            } else {
                const int g2 = g - G3;
                const float bias = bihb[g2] + (g2 < 2 * Hq ? bhhb[g2] : 0.0f);
                xpb[(size_t)m * G3 + g2] = v + bias;
            }
        }
    }
}

// ---------------------------------------------------------------------------
// GRU recurrence. One block per (dir, batch) chain: 128 blocks x 768 threads.
// Thread j computes gate-dot j each step. Weights wt[k][j]: k<RREG in VGPRs,
// rest streamed from L2 (coalesced, L2-resident).
// h[t] is written IN PLACE into xp[t][0..255] (each thread reads xp[t][j]
// before the sole writer -- itself -- overwrites it; no cross-thread hazard).
__global__ __launch_bounds__(768, 3) void gru_kernel(
    const float* __restrict__ wt0,
    float* __restrict__ xpf, float* __restrict__ xpb,
    const float* __restrict__ bhhf, const float* __restrict__ bhhb)
{
    __shared__ float sh_h[Hq];
    __shared__ float sh_g[G3];
    __shared__ float sh_x[G3];
    const int bid = blockIdx.x;
    const int dir = bid >> 6;
    const int b   = bid & 63;
    const int j   = threadIdx.x;
    const float* wt = wt0 + (size_t)dir * (G3 * Hq);
    float* xp = (dir ? xpb : xpf) + (size_t)b * Tt * G3;

    float wreg[RREG];
#pragma unroll
    for (int r = 0; r < RREG; ++r) wreg[r] = wt[(size_t)r * G3 + j];
    const float* wstr = wt + (size_t)RREG * G3 + j;

    float bhn = 0.0f;
    if (j < Hq) bhn = (dir ? bhhb : bhhf)[2 * Hq + j];
    if (j < Hq) sh_h[j] = 0.0f;

    for (int ti = 0; ti < Tt; ++ti) {
        const int t = dir ? (Tt - 1 - ti) : ti;
        __syncthreads();                       // protects sh_h/sh_x/sh_g reuse
        sh_x[j] = xp[(size_t)t * G3 + j];
        float acc = 0.0f;
#pragma unroll
        for (int r4 = 0; r4 < RREG / 4; ++r4) {
            const float4 hv = *(const float4*)(sh_h + r4 * 4);
            acc += hv.x * wreg[r4 * 4 + 0];
            acc += hv.y * wreg[r4 * 4 + 1];
            acc += hv.z * wreg[r4 * 4 + 2];
            acc += hv.w * wreg[r4 * 4 + 3];
        }
#pragma unroll 2
        for (int kc = 0; kc < NSTREAM / 8; ++kc) {
            const float w0 = wstr[(size_t)(kc * 8 + 0) * G3];
            const float w1 = wstr[(size_t)(kc * 8 + 1) * G3];
            const float w2 = wstr[(size_t)(kc * 8 + 2) * G3];
            const float w3 = wstr[(size_t)(kc * 8 + 3) * G3];
            const float w4 = wstr[(size_t)(kc * 8 + 4) * G3];
            const float w5 = wstr[(size_t)(kc * 8 + 5) * G3];
            const float w6 = wstr[(size_t)(kc * 8 + 6) * G3];
            const float w7 = wstr[(size_t)(kc * 8 + 7) * G3];
            const float4 h0 = *(const float4*)(sh_h + RREG + kc * 8);
            const float4 h1 = *(const float4*)(sh_h + RREG + kc * 8 + 4);
            acc += h0.x * w0 + h0.y * w1 + h0.z * w2 + h0.w * w3;
            acc += h1.x * w4 + h1.y * w5 + h1.z * w6 + h1.w * w7;
        }
        sh_g[j] = acc;
        __syncthreads();
        if (j < Hq) {
            const float xr = sh_x[j], xz = sh_x[Hq + j], xn = sh_x[2 * Hq + j];
            const float hr = sh_g[j], hz = sh_g[Hq + j];
            const float hn = sh_g[2 * Hq + j] + bhn;   // b_hh n-part multiplied by r
            const float r = 1.0f / (1.0f + expf(-(xr + hr)));
            const float z = 1.0f / (1.0f + expf(-(xz + hz)));
            const float n = tanhf(xn + r * hn);
            const float hprev = sh_h[j];
            const float hnew = (1.0f - z) * n + z * hprev;
            sh_h[j] = hnew;
            xp[(size_t)t * G3 + j] = hnew;     // in-place h store
        }
    }
}

// ---------------------------------------------------------------------------
// em[m][n] = sum_k hf[m][k]*fcw[n][k] + sum_k hb[m][k]*fcw[n][256+k] + fcb[n]
// hf/hb live in the first 256 floats of each 768-float xp row.
__global__ __launch_bounds__(256) void em_kernel(
    const float* __restrict__ hf, const float* __restrict__ hb,
    const float* __restrict__ fcw, const float* __restrict__ fcb,
    float* __restrict__ em)
{
    __shared__ float ht[16][129];
    __shared__ float wt2[16][129];
    const int m0 = blockIdx.x * 16;
    const int tid = threadIdx.x;
    const int r = tid >> 4, n = tid & 15;
    float acc = 0.0f;
    for (int s = 0; s < 2; ++s) {
        const float* src = s ? hb : hf;
        for (int kc = 0; kc < Hq; kc += 128) {
            __syncthreads();
            for (int it = 0; it < 8; ++it) {
                const int l = it * 256 + tid;
                const int rr = l >> 7, k = l & 127;
                ht[rr][k] = src[(size_t)(m0 + rr) * G3 + kc + k];
            }
            for (int it = 0; it < 8; ++it) {
                const int l = it * 256 + tid;
                const int rr = l >> 7, k = l & 127;
                wt2[rr][k] = fcw[(size_t)rr * (2 * Hq) + s * Hq + kc + k];
            }
            __syncthreads();
            for (int k = 0; k < 128; ++k)
                acc += ht[r][k] * wt2[n][k];
        }
    }
    em[(size_t)(m0 + r) * KK + n] = acc + fcb[n];
}

// ---------------------------------------------------------------------------
// Viterbi: one wave per batch. Lanes 0..15 = states. Backpointers in LDS.
__global__ __launch_bounds__(64) void viterbi_kernel(
    const float* __restrict__ em, const int* __restrict__ y,
    const float* __restrict__ tr, float* __restrict__ out)
{
    __shared__ unsigned char bps[(Tt - 1) * KK];
    __shared__ unsigned char msk[Tt];
    const int b = blockIdx.x;
    const int lane = threadIdx.x;
    if (lane >= KK) return;
    const int j = lane;
    float tc[KK];
#pragma unroll
    for (int i = 0; i < KK; ++i) tc[i] = tr[i * KK + j];
    const float* erow = em + (size_t)b * Tt * KK;
    const int* yrow = y + b * Tt;
    float s = tr[1 * KK + j] + erow[j];            // BOS row + em[:,0]
    if (j == 0) msk[0] = (unsigned char)(yrow[0] != 0);
    float e1 = erow[1 * KK + j];  int y1v = yrow[1];
    float e2 = erow[2 * KK + j];  int y2v = yrow[2];
    for (int t = 1; t < Tt; ++t) {
        const float e = e1; const int yt = y1v;
        e1 = e2; y1v = y2v;
        if (t + 2 < Tt) { e2 = erow[(size_t)(t + 2) * KK + j]; y2v = yrow[t + 2]; }
        float best = -3.0e38f; int arg = 0;
#pragma unroll
        for (int i = 0; i < KK; ++i) {
            const float si = __shfl(s, i, KK);
            const float c = si + tc[i];
            if (c > best) { best = c; arg = i; }   // strict >, first-max = argmax
        }
        best += e;
        const bool m = (yt != 0);
        if (m) s = best;
        bps[(t - 1) * KK + j] = m ? (unsigned char)arg : (unsigned char)j;
        if (j == 0) msk[t] = (unsigned char)m;
    }
    s += tr[j * KK + 2];                           // + trans[:,EOS]
    float bs = -3.0e38f; int bt = 0;
#pragma unroll
    for (int i = 0; i < KK; ++i) {
        const float si = __shfl(s, i, KK);
        if (si > bs) { bs = si; bt = i; }
    }
    if (j == 0) {
        out[b] = bs;
        float* path = out + Bb + (size_t)b * Tt;
        int tag = bt;
        path[Tt - 1] = msk[Tt - 1] ? (float)tag : 0.0f;
        for (int t = Tt - 2; t >= 0; --t) {
            tag = bps[t * KK + tag];
            path[t] = msk[t] ? (float)tag : 0.0f;
        }
    }
}

// Diagnostic fallback if workspace is too small: park ws_size in out[0..63].
__global__ void ws_report_kernel(float* out, float v)
{
    if (threadIdx.x < 64) out[threadIdx.x] = v;
}

// ---------------------------------------------------------------------------
extern "C" void kernel_launch(void* const* d_in, const int* in_sizes, int n_in,
                              void* d_out, int out_size, void* d_ws, size_t ws_size,
                              hipStream_t stream)
{
    const int*   x     = (const int*)d_in[0];
    const int*   y     = (const int*)d_in[1];
    const float* emb   = (const float*)d_in[2];
    const float* wihf  = (const float*)d_in[3];
    const float* whhf  = (const float*)d_in[4];
    const float* bihf  = (const float*)d_in[5];
    const float* bhhf  = (const float*)d_in[6];
    const float* wihb  = (const float*)d_in[7];
    const float* whhb  = (const float*)d_in[8];
    const float* bihb  = (const float*)d_in[9];
    const float* bhhb  = (const float*)d_in[10];
    const float* fcw   = (const float*)d_in[11];
    const float* fcb   = (const float*)d_in[12];
    const float* trans = (const float*)d_in[13];
    float* out = (float*)d_out;
    float* ws  = (float*)d_ws;

    if (ws_size < WS_FLOATS * sizeof(float)) {
        ws_report_kernel<<<1, 64, 0, stream>>>(out, (float)ws_size);
        return;
    }

    transpose_whh<<<768, 256, 0, stream>>>(whhf, ws + OFF_WTF);
    transpose_whh<<<768, 256, 0, stream>>>(whhb, ws + OFF_WTB);
    proj_kernel<<<12288, 256, 0, stream>>>(x, emb, wihf, wihb,
                                           bihf, bhhf, bihb, bhhb,
                                           ws + OFF_XPF, ws + OFF_XPB);
    gru_kernel<<<128, 768, 0, stream>>>(ws + OFF_WTF, ws + OFF_XPF, ws + OFF_XPB,
                                        bhhf, bhhb);
    em_kernel<<<2048, 256, 0, stream>>>(ws + OFF_XPF, ws + OFF_XPB, fcw, fcb,
                                        ws + OFF_EM);
    viterbi_kernel<<<64, 64, 0, stream>>>(ws + OFF_EM, y, trans, out);
}